// Round 4
// baseline (64.951 us; speedup 1.0000x reference)
//
#include <hip/hip_runtime.h>

typedef int   __attribute__((ext_vector_type(4))) i32x4;
typedef float __attribute__((ext_vector_type(4))) f32x4;

constexpr int B_ = 8;
constexpr int N_ = 8192;
constexpr int K_ = 100;
constexpr int PER_BATCH = N_ * K_;                      // 819200 elements
constexpr int QUADS_PER_BATCH = PER_BATCH / 4;          // 204800
constexpr int BLOCK = 256;
constexpr int QPT = 2;                                  // quads per thread (8 elems)
constexpr int QUADS_PER_BLOCK = BLOCK * QPT;            // 512
constexpr int BLOCKS_PER_BATCH = QUADS_PER_BATCH / QUADS_PER_BLOCK; // 400 exact
constexpr int GRID = B_ * BLOCKS_PER_BATCH;             // 3200

constexpr float RMIN2 = 0.01f;   // 0.1^2
constexpr float RMAX2 = 4.0f;    // 2.0^2

__global__ __launch_bounds__(BLOCK)
void repulsive_prior_kernel(const float* __restrict__ positions,  // [B,N,3]
                            const float* __restrict__ cell,       // [B,3,3]
                            const float* __restrict__ offsets,    // [B,N,K,3]
                            const int*   __restrict__ neighbors,  // [B,N,K]
                            const int*   __restrict__ mask,       // [B,N,K]
                            float* __restrict__ out)              // [B]
{
    const int bid   = blockIdx.x;
    const int b     = bid & 7;          // 8 batches <-> 8 XCDs (L2 locality for gathers)
    const int chunk = bid >> 3;         // 0..399
    const int qbase = chunk * QUADS_PER_BLOCK;

    const float* cb = cell + b * 9;
    const float c00 = cb[0], c01 = cb[1], c02 = cb[2];
    const float c10 = cb[3], c11 = cb[4], c12 = cb[5];
    const float c20 = cb[6], c21 = cb[7], c22 = cb[8];

    const float* __restrict__ pos_b = positions + (size_t)b * N_ * 3;
    const float* __restrict__ off_b = offsets   + (size_t)b * PER_BATCH * 3;
    const int*   __restrict__ nb_b  = neighbors + (size_t)b * PER_BATCH;
    const int*   __restrict__ mk_b  = mask      + (size_t)b * PER_BATCH;

    const int qid0 = qbase + (int)threadIdx.x;            // quad ids, BLOCK apart
    const int qid1 = qid0 + BLOCK;

    // ---- phase 1: all streaming loads (read-once -> nontemporal) ----
    const i32x4 nb0 = __builtin_nontemporal_load((const i32x4*)(nb_b  + 4 * (size_t)qid0));
    const i32x4 nb1 = __builtin_nontemporal_load((const i32x4*)(nb_b  + 4 * (size_t)qid1));
    const i32x4 mk0 = __builtin_nontemporal_load((const i32x4*)(mk_b  + 4 * (size_t)qid0));
    const i32x4 mk1 = __builtin_nontemporal_load((const i32x4*)(mk_b  + 4 * (size_t)qid1));
    const f32x4 oa0 = __builtin_nontemporal_load((const f32x4*)(off_b + 12 * (size_t)qid0));
    const f32x4 ob0 = __builtin_nontemporal_load((const f32x4*)(off_b + 12 * (size_t)qid0 + 4));
    const f32x4 oc0 = __builtin_nontemporal_load((const f32x4*)(off_b + 12 * (size_t)qid0 + 8));
    const f32x4 oa1 = __builtin_nontemporal_load((const f32x4*)(off_b + 12 * (size_t)qid1));
    const f32x4 ob1 = __builtin_nontemporal_load((const f32x4*)(off_b + 12 * (size_t)qid1 + 4));
    const f32x4 oc1 = __builtin_nontemporal_load((const f32x4*)(off_b + 12 * (size_t)qid1 + 8));

    // ---- phase 2: pos_i (row-coherent) + 8 random gathers ----
    const int n0 = qid0 / 25;   // 25 quads per row of K=100
    const int n1 = qid1 / 25;
    const float pix0 = pos_b[3 * n0 + 0], piy0 = pos_b[3 * n0 + 1], piz0 = pos_b[3 * n0 + 2];
    const float pix1 = pos_b[3 * n1 + 0], piy1 = pos_b[3 * n1 + 1], piz1 = pos_b[3 * n1 + 2];

    const int j00 = nb0.x, j01 = nb0.y, j02 = nb0.z, j03 = nb0.w;
    const int j10 = nb1.x, j11 = nb1.y, j12 = nb1.z, j13 = nb1.w;

    const float ax0 = pos_b[3*j00+0], ay0 = pos_b[3*j00+1], az0 = pos_b[3*j00+2];
    const float ax1 = pos_b[3*j01+0], ay1 = pos_b[3*j01+1], az1 = pos_b[3*j01+2];
    const float ax2 = pos_b[3*j02+0], ay2 = pos_b[3*j02+1], az2 = pos_b[3*j02+2];
    const float ax3 = pos_b[3*j03+0], ay3 = pos_b[3*j03+1], az3 = pos_b[3*j03+2];
    const float bx0 = pos_b[3*j10+0], by0 = pos_b[3*j10+1], bz0 = pos_b[3*j10+2];
    const float bx1 = pos_b[3*j11+0], by1 = pos_b[3*j11+1], bz1 = pos_b[3*j11+2];
    const float bx2 = pos_b[3*j12+0], by2 = pos_b[3*j12+1], bz2 = pos_b[3*j12+2];
    const float bx3 = pos_b[3*j13+0], by3 = pos_b[3*j13+1], bz3 = pos_b[3*j13+2];

    // ---- phase 3: math ----
    float acc = 0.0f;
    auto elem = [&](int m, float o0, float o1, float o2,
                    float pix, float piy, float piz,
                    float pjx, float pjy, float pjz) {
        const float vx = pjx + o0 * c00 + o1 * c10 + o2 * c20 - pix;
        const float vy = pjy + o0 * c01 + o1 * c11 + o2 * c21 - piy;
        const float vz = pjz + o0 * c02 + o1 * c12 + o2 * c22 - piz;
        const float sq = vx * vx + vy * vy + vz * vz;
        const bool keep = (m > 0) & (sq >= RMIN2) & (sq <= RMAX2);
        acc += keep ? (1.0f / sq) : 0.0f;
    };

    elem(mk0.x, oa0.x, oa0.y, oa0.z, pix0, piy0, piz0, ax0, ay0, az0);
    elem(mk0.y, oa0.w, ob0.x, ob0.y, pix0, piy0, piz0, ax1, ay1, az1);
    elem(mk0.z, ob0.z, ob0.w, oc0.x, pix0, piy0, piz0, ax2, ay2, az2);
    elem(mk0.w, oc0.y, oc0.z, oc0.w, pix0, piy0, piz0, ax3, ay3, az3);
    elem(mk1.x, oa1.x, oa1.y, oa1.z, pix1, piy1, piz1, bx0, by0, bz0);
    elem(mk1.y, oa1.w, ob1.x, ob1.y, pix1, piy1, piz1, bx1, by1, bz1);
    elem(mk1.z, ob1.z, ob1.w, oc1.x, pix1, piy1, piz1, bx2, by2, bz2);
    elem(mk1.w, oc1.y, oc1.z, oc1.w, pix1, piy1, piz1, bx3, by3, bz3);

    // wave64 reduce
    #pragma unroll
    for (int off = 32; off > 0; off >>= 1)
        acc += __shfl_down(acc, off, 64);

    __shared__ float wsum[BLOCK / 64];
    const int wave = threadIdx.x >> 6;
    const int lane = threadIdx.x & 63;
    if (lane == 0) wsum[wave] = acc;
    __syncthreads();
    if (threadIdx.x == 0) {
        float s = 0.0f;
        #pragma unroll
        for (int w = 0; w < BLOCK / 64; ++w) s += wsum[w];
        atomicAdd(&out[b], 0.5f * s);
    }
}

extern "C" void kernel_launch(void* const* d_in, const int* in_sizes, int n_in,
                              void* d_out, int out_size, void* d_ws, size_t ws_size,
                              hipStream_t stream) {
    const float* positions = (const float*)d_in[0];
    const float* cell      = (const float*)d_in[1];
    const float* offsets   = (const float*)d_in[2];
    const int*   neighbors = (const int*)d_in[3];
    const int*   mask      = (const int*)d_in[4];
    float* out = (float*)d_out;

    (void)hipMemsetAsync(out, 0, out_size * sizeof(float), stream);

    repulsive_prior_kernel<<<GRID, BLOCK, 0, stream>>>(
        positions, cell, offsets, neighbors, mask, out);
}

// Round 5
// 62.314 us; speedup vs baseline: 1.0423x; 1.0423x over previous
//
#include <hip/hip_runtime.h>

typedef int   __attribute__((ext_vector_type(4))) i32x4;
typedef float __attribute__((ext_vector_type(4))) f32x4;

constexpr int B_ = 8;
constexpr int N_ = 8192;
constexpr int K_ = 100;
constexpr int PER_BATCH = N_ * K_;                      // 819200 elements
constexpr int QUADS_PER_BATCH = PER_BATCH / 4;          // 204800
constexpr int BLOCK = 256;
constexpr int QPT = 2;                                  // quads per thread (8 elems)
constexpr int QUADS_PER_BLOCK = BLOCK * QPT;            // 512
constexpr int BLOCKS_PER_BATCH = QUADS_PER_BATCH / QUADS_PER_BLOCK; // 400 exact
constexpr int GRID = B_ * BLOCKS_PER_BATCH;             // 3200

constexpr float RMIN2 = 0.01f;   // 0.1^2
constexpr float RMAX2 = 4.0f;    // 2.0^2

// ---- pre-pass: pack positions [B,N,3] -> [B,N,4] (16B-aligned gathers) ----
__global__ __launch_bounds__(256)
void pack_positions_kernel(const float* __restrict__ pos, float* __restrict__ pos4)
{
    const int idx = blockIdx.x * 256 + (int)threadIdx.x;   // over B_*N_ (exact)
    const float x = pos[3 * (size_t)idx + 0];
    const float y = pos[3 * (size_t)idx + 1];
    const float z = pos[3 * (size_t)idx + 2];
    f32x4 v; v.x = x; v.y = y; v.z = z; v.w = 0.0f;
    *(f32x4*)(pos4 + 4 * (size_t)idx) = v;
}

template <bool PACKED>
__global__ __launch_bounds__(BLOCK)
void repulsive_prior_kernel(const float* __restrict__ positions,  // PACKED ? [B,N,4] : [B,N,3]
                            const float* __restrict__ cell,       // [B,3,3]
                            const float* __restrict__ offsets,    // [B,N,K,3]
                            const int*   __restrict__ neighbors,  // [B,N,K]
                            const int*   __restrict__ mask,       // [B,N,K]
                            float* __restrict__ out)              // [B]
{
    const int bid   = blockIdx.x;
    const int b     = bid & 7;          // 8 batches <-> 8 XCDs (L2 locality for gathers)
    const int chunk = bid >> 3;         // 0..399
    const int qbase = chunk * QUADS_PER_BLOCK;

    const float* cb = cell + b * 9;
    const float c00 = cb[0], c01 = cb[1], c02 = cb[2];
    const float c10 = cb[3], c11 = cb[4], c12 = cb[5];
    const float c20 = cb[6], c21 = cb[7], c22 = cb[8];

    constexpr int PSTRIDE = PACKED ? 4 : 3;
    const float* __restrict__ pos_b = positions + (size_t)b * N_ * PSTRIDE;
    const float* __restrict__ off_b = offsets   + (size_t)b * PER_BATCH * 3;
    const int*   __restrict__ nb_b  = neighbors + (size_t)b * PER_BATCH;
    const int*   __restrict__ mk_b  = mask      + (size_t)b * PER_BATCH;

    const int qid0 = qbase + (int)threadIdx.x;            // quad ids, BLOCK apart
    const int qid1 = qid0 + BLOCK;

    // ---- phase 1: coalesced streaming loads ----
    const i32x4 nb0 = *(const i32x4*)(nb_b  + 4 * (size_t)qid0);
    const i32x4 nb1 = *(const i32x4*)(nb_b  + 4 * (size_t)qid1);
    const i32x4 mk0 = *(const i32x4*)(mk_b  + 4 * (size_t)qid0);
    const i32x4 mk1 = *(const i32x4*)(mk_b  + 4 * (size_t)qid1);
    const f32x4 oa0 = *(const f32x4*)(off_b + 12 * (size_t)qid0);
    const f32x4 ob0 = *(const f32x4*)(off_b + 12 * (size_t)qid0 + 4);
    const f32x4 oc0 = *(const f32x4*)(off_b + 12 * (size_t)qid0 + 8);
    const f32x4 oa1 = *(const f32x4*)(off_b + 12 * (size_t)qid1);
    const f32x4 ob1 = *(const f32x4*)(off_b + 12 * (size_t)qid1 + 4);
    const f32x4 oc1 = *(const f32x4*)(off_b + 12 * (size_t)qid1 + 8);

    // ---- phase 2: pos_i (row-coherent) + 8 random gathers ----
    auto ldpos = [&](int row, float& x, float& y, float& z) {
        if constexpr (PACKED) {
            const f32x4 p = *(const f32x4*)(pos_b + 4 * (size_t)row);
            x = p.x; y = p.y; z = p.z;
        } else {
            x = pos_b[3 * (size_t)row + 0];
            y = pos_b[3 * (size_t)row + 1];
            z = pos_b[3 * (size_t)row + 2];
        }
    };

    const int n0 = qid0 / 25;   // 25 quads per row of K=100
    const int n1 = qid1 / 25;
    float pix0, piy0, piz0, pix1, piy1, piz1;
    ldpos(n0, pix0, piy0, piz0);
    ldpos(n1, pix1, piy1, piz1);

    float ax0,ay0,az0, ax1,ay1,az1, ax2,ay2,az2, ax3,ay3,az3;
    float bx0,by0,bz0, bx1,by1,bz1, bx2,by2,bz2, bx3,by3,bz3;
    ldpos(nb0.x, ax0, ay0, az0);
    ldpos(nb0.y, ax1, ay1, az1);
    ldpos(nb0.z, ax2, ay2, az2);
    ldpos(nb0.w, ax3, ay3, az3);
    ldpos(nb1.x, bx0, by0, bz0);
    ldpos(nb1.y, bx1, by1, bz1);
    ldpos(nb1.z, bx2, by2, bz2);
    ldpos(nb1.w, bx3, by3, bz3);

    // ---- phase 3: math ----
    float acc = 0.0f;
    auto elem = [&](int m, float o0, float o1, float o2,
                    float pix, float piy, float piz,
                    float pjx, float pjy, float pjz) {
        const float vx = pjx + o0 * c00 + o1 * c10 + o2 * c20 - pix;
        const float vy = pjy + o0 * c01 + o1 * c11 + o2 * c21 - piy;
        const float vz = pjz + o0 * c02 + o1 * c12 + o2 * c22 - piz;
        const float sq = vx * vx + vy * vy + vz * vz;
        const bool keep = (m > 0) & (sq >= RMIN2) & (sq <= RMAX2);
        acc += keep ? (1.0f / sq) : 0.0f;
    };

    elem(mk0.x, oa0.x, oa0.y, oa0.z, pix0, piy0, piz0, ax0, ay0, az0);
    elem(mk0.y, oa0.w, ob0.x, ob0.y, pix0, piy0, piz0, ax1, ay1, az1);
    elem(mk0.z, ob0.z, ob0.w, oc0.x, pix0, piy0, piz0, ax2, ay2, az2);
    elem(mk0.w, oc0.y, oc0.z, oc0.w, pix0, piy0, piz0, ax3, ay3, az3);
    elem(mk1.x, oa1.x, oa1.y, oa1.z, pix1, piy1, piz1, bx0, by0, bz0);
    elem(mk1.y, oa1.w, ob1.x, ob1.y, pix1, piy1, piz1, bx1, by1, bz1);
    elem(mk1.z, ob1.z, ob1.w, oc1.x, pix1, piy1, piz1, bx2, by2, bz2);
    elem(mk1.w, oc1.y, oc1.z, oc1.w, pix1, piy1, piz1, bx3, by3, bz3);

    // wave64 reduce
    #pragma unroll
    for (int off = 32; off > 0; off >>= 1)
        acc += __shfl_down(acc, off, 64);

    __shared__ float wsum[BLOCK / 64];
    const int wave = threadIdx.x >> 6;
    const int lane = threadIdx.x & 63;
    if (lane == 0) wsum[wave] = acc;
    __syncthreads();
    if (threadIdx.x == 0) {
        float s = 0.0f;
        #pragma unroll
        for (int w = 0; w < BLOCK / 64; ++w) s += wsum[w];
        atomicAdd(&out[b], 0.5f * s);
    }
}

extern "C" void kernel_launch(void* const* d_in, const int* in_sizes, int n_in,
                              void* d_out, int out_size, void* d_ws, size_t ws_size,
                              hipStream_t stream) {
    const float* positions = (const float*)d_in[0];
    const float* cell      = (const float*)d_in[1];
    const float* offsets   = (const float*)d_in[2];
    const int*   neighbors = (const int*)d_in[3];
    const int*   mask      = (const int*)d_in[4];
    float* out = (float*)d_out;

    (void)hipMemsetAsync(out, 0, out_size * sizeof(float), stream);

    const size_t packed_bytes = (size_t)B_ * N_ * 4 * sizeof(float);   // 512 KB
    if (ws_size >= packed_bytes) {
        float* pos4 = (float*)d_ws;
        pack_positions_kernel<<<(B_ * N_) / 256, 256, 0, stream>>>(positions, pos4);
        repulsive_prior_kernel<true><<<GRID, BLOCK, 0, stream>>>(
            pos4, cell, offsets, neighbors, mask, out);
    } else {
        repulsive_prior_kernel<false><<<GRID, BLOCK, 0, stream>>>(
            positions, cell, offsets, neighbors, mask, out);
    }
}

// Round 6
// 55.358 us; speedup vs baseline: 1.1733x; 1.1256x over previous
//
#include <hip/hip_runtime.h>

typedef int   __attribute__((ext_vector_type(4))) i32x4;
typedef float __attribute__((ext_vector_type(4))) f32x4;

constexpr int B_ = 8;
constexpr int N_ = 8192;
constexpr int K_ = 100;
constexpr int PER_BATCH = N_ * K_;                      // 819200 elements
constexpr int QUADS_PER_BATCH = PER_BATCH / 4;          // 204800
constexpr int BLOCK = 256;
constexpr int QPT = 4;                                  // quads per thread (16 elems)
constexpr int QUADS_PER_BLOCK = BLOCK * QPT;            // 1024
constexpr int BLOCKS_PER_BATCH = QUADS_PER_BATCH / QUADS_PER_BLOCK; // 200 exact
constexpr int GRID = B_ * BLOCKS_PER_BATCH;             // 1600 -> 6400 waves, one residency round

constexpr float RMIN2 = 0.01f;   // 0.1^2
constexpr float RMAX2 = 4.0f;    // 2.0^2

// ---- pre-pass: pack positions [B,N,3] -> [B,N,4] (16B-aligned gathers) ----
__global__ __launch_bounds__(256)
void pack_positions_kernel(const float* __restrict__ pos, float* __restrict__ pos4)
{
    const int idx = blockIdx.x * 256 + (int)threadIdx.x;   // over B_*N_ (exact)
    const float x = pos[3 * (size_t)idx + 0];
    const float y = pos[3 * (size_t)idx + 1];
    const float z = pos[3 * (size_t)idx + 2];
    f32x4 v; v.x = x; v.y = y; v.z = z; v.w = 0.0f;
    *(f32x4*)(pos4 + 4 * (size_t)idx) = v;
}

__global__ __launch_bounds__(BLOCK)
void repulsive_prior_kernel(const float* __restrict__ pos4,       // [B,N,4] packed
                            const float* __restrict__ cell,       // [B,3,3]
                            const float* __restrict__ offsets,    // [B,N,K,3]
                            const int*   __restrict__ neighbors,  // [B,N,K]
                            const int*   __restrict__ mask,       // [B,N,K]
                            float* __restrict__ out)              // [B]
{
    const int bid   = blockIdx.x;
    const int b     = bid & 7;          // 8 batches <-> 8 XCDs (L2 locality for gathers)
    const int chunk = bid >> 3;         // 0..199
    const int qbase = chunk * QUADS_PER_BLOCK;

    const float* cb = cell + b * 9;
    const float c00 = cb[0], c01 = cb[1], c02 = cb[2];
    const float c10 = cb[3], c11 = cb[4], c12 = cb[5];
    const float c20 = cb[6], c21 = cb[7], c22 = cb[8];

    const float* __restrict__ pos_b = pos4      + (size_t)b * N_ * 4;
    const float* __restrict__ off_b = offsets   + (size_t)b * PER_BATCH * 3;
    const int*   __restrict__ nb_b  = neighbors + (size_t)b * PER_BATCH;
    const int*   __restrict__ mk_b  = mask      + (size_t)b * PER_BATCH;

    const int tid  = (int)threadIdx.x;
    const int qidA = qbase + 0 * BLOCK + tid;
    const int qidB = qbase + 1 * BLOCK + tid;
    const int qidC = qbase + 2 * BLOCK + tid;
    const int qidD = qbase + 3 * BLOCK + tid;

    // ---- all neighbor-index loads first: gather addresses in flight ASAP ----
    const i32x4 nbA = *(const i32x4*)(nb_b + 4 * (size_t)qidA);
    const i32x4 nbB = *(const i32x4*)(nb_b + 4 * (size_t)qidB);
    const i32x4 nbC = *(const i32x4*)(nb_b + 4 * (size_t)qidC);
    const i32x4 nbD = *(const i32x4*)(nb_b + 4 * (size_t)qidD);

    float acc = 0.0f;

    auto elem = [&](int m, float o0, float o1, float o2,
                    float pix, float piy, float piz, f32x4 pj) {
        const float vx = pj.x + o0 * c00 + o1 * c10 + o2 * c20 - pix;
        const float vy = pj.y + o0 * c01 + o1 * c11 + o2 * c21 - piy;
        const float vz = pj.z + o0 * c02 + o1 * c12 + o2 * c22 - piz;
        const float sq = vx * vx + vy * vy + vz * vz;
        const bool keep = (m > 0) & (sq >= RMIN2) & (sq <= RMAX2);
        acc += keep ? (1.0f / sq) : 0.0f;
    };

    auto body = [&](int qid0, int qid1, const i32x4 nb0, const i32x4 nb1) {
        // streaming loads for this body
        const i32x4 mk0 = *(const i32x4*)(mk_b  + 4 * (size_t)qid0);
        const i32x4 mk1 = *(const i32x4*)(mk_b  + 4 * (size_t)qid1);
        const f32x4 oa0 = *(const f32x4*)(off_b + 12 * (size_t)qid0);
        const f32x4 ob0 = *(const f32x4*)(off_b + 12 * (size_t)qid0 + 4);
        const f32x4 oc0 = *(const f32x4*)(off_b + 12 * (size_t)qid0 + 8);
        const f32x4 oa1 = *(const f32x4*)(off_b + 12 * (size_t)qid1);
        const f32x4 ob1 = *(const f32x4*)(off_b + 12 * (size_t)qid1 + 4);
        const f32x4 oc1 = *(const f32x4*)(off_b + 12 * (size_t)qid1 + 8);

        // pos_i (row-coherent) + 8 packed random gathers (one dwordx4 each)
        const int n0 = qid0 / 25;   // 25 quads per row of K=100
        const int n1 = qid1 / 25;
        const f32x4 pi0 = *(const f32x4*)(pos_b + 4 * (size_t)n0);
        const f32x4 pi1 = *(const f32x4*)(pos_b + 4 * (size_t)n1);

        const f32x4 pa0 = *(const f32x4*)(pos_b + 4 * (size_t)nb0.x);
        const f32x4 pa1 = *(const f32x4*)(pos_b + 4 * (size_t)nb0.y);
        const f32x4 pa2 = *(const f32x4*)(pos_b + 4 * (size_t)nb0.z);
        const f32x4 pa3 = *(const f32x4*)(pos_b + 4 * (size_t)nb0.w);
        const f32x4 pb0 = *(const f32x4*)(pos_b + 4 * (size_t)nb1.x);
        const f32x4 pb1 = *(const f32x4*)(pos_b + 4 * (size_t)nb1.y);
        const f32x4 pb2 = *(const f32x4*)(pos_b + 4 * (size_t)nb1.z);
        const f32x4 pb3 = *(const f32x4*)(pos_b + 4 * (size_t)nb1.w);

        elem(mk0.x, oa0.x, oa0.y, oa0.z, pi0.x, pi0.y, pi0.z, pa0);
        elem(mk0.y, oa0.w, ob0.x, ob0.y, pi0.x, pi0.y, pi0.z, pa1);
        elem(mk0.z, ob0.z, ob0.w, oc0.x, pi0.x, pi0.y, pi0.z, pa2);
        elem(mk0.w, oc0.y, oc0.z, oc0.w, pi0.x, pi0.y, pi0.z, pa3);
        elem(mk1.x, oa1.x, oa1.y, oa1.z, pi1.x, pi1.y, pi1.z, pb0);
        elem(mk1.y, oa1.w, ob1.x, ob1.y, pi1.x, pi1.y, pi1.z, pb1);
        elem(mk1.z, ob1.z, ob1.w, oc1.x, pi1.x, pi1.y, pi1.z, pb2);
        elem(mk1.w, oc1.y, oc1.z, oc1.w, pi1.x, pi1.y, pi1.z, pb3);
    };

    body(qidA, qidB, nbA, nbB);
    body(qidC, qidD, nbC, nbD);

    // wave64 reduce
    #pragma unroll
    for (int off = 32; off > 0; off >>= 1)
        acc += __shfl_down(acc, off, 64);

    __shared__ float wsum[BLOCK / 64];
    const int wave = threadIdx.x >> 6;
    const int lane = threadIdx.x & 63;
    if (lane == 0) wsum[wave] = acc;
    __syncthreads();
    if (threadIdx.x == 0) {
        float s = 0.0f;
        #pragma unroll
        for (int w = 0; w < BLOCK / 64; ++w) s += wsum[w];
        atomicAdd(&out[b], 0.5f * s);
    }
}

extern "C" void kernel_launch(void* const* d_in, const int* in_sizes, int n_in,
                              void* d_out, int out_size, void* d_ws, size_t ws_size,
                              hipStream_t stream) {
    const float* positions = (const float*)d_in[0];
    const float* cell      = (const float*)d_in[1];
    const float* offsets   = (const float*)d_in[2];
    const int*   neighbors = (const int*)d_in[3];
    const int*   mask      = (const int*)d_in[4];
    float* out = (float*)d_out;

    (void)hipMemsetAsync(out, 0, out_size * sizeof(float), stream);

    float* pos4 = (float*)d_ws;    // 512 KB needed; ws is MBs
    pack_positions_kernel<<<(B_ * N_) / 256, 256, 0, stream>>>(positions, pos4);
    repulsive_prior_kernel<<<GRID, BLOCK, 0, stream>>>(
        pos4, cell, offsets, neighbors, mask, out);
}

// Round 7
// 32.115 us; speedup vs baseline: 2.0224x; 1.7237x over previous
//
#include <hip/hip_runtime.h>

typedef int   __attribute__((ext_vector_type(4))) i32x4;
typedef float __attribute__((ext_vector_type(4))) f32x4;

constexpr int B_ = 8;
constexpr int N_ = 8192;
constexpr int K_ = 100;
constexpr int PER_BATCH = N_ * K_;                 // 819200 elements
constexpr int QUADS_PER_BATCH = PER_BATCH / 4;     // 204800 quads (K=100 divisible by 4)
constexpr int THREADS = 1024;                      // 16 waves
constexpr int BLOCKS_PER_BATCH = 32;
constexpr int GRID = B_ * BLOCKS_PER_BATCH;        // 256 blocks -> 1/CU (96KB LDS)
constexpr int QUADS_PER_BLOCK = QUADS_PER_BATCH / BLOCKS_PER_BATCH; // 6400
constexpr int FULL_ITERS = QUADS_PER_BLOCK / THREADS;               // 6
constexpr int TAIL = QUADS_PER_BLOCK - FULL_ITERS * THREADS;        // 256

constexpr float RMIN2 = 0.01f;   // 0.1^2
constexpr float RMAX2 = 4.0f;    // 2.0^2

__global__ __launch_bounds__(THREADS)
void repulsive_prior_kernel(const float* __restrict__ positions,  // [B,N,3]
                            const float* __restrict__ cell,       // [B,3,3]
                            const float* __restrict__ offsets,    // [B,N,K,3]
                            const int*   __restrict__ neighbors,  // [B,N,K]
                            const int*   __restrict__ mask,       // [B,N,K]
                            float* __restrict__ out)              // [B]
{
    __shared__ float sx[N_];   // 32 KB
    __shared__ float sy[N_];   // 32 KB
    __shared__ float sz[N_];   // 32 KB
    __shared__ float wsum[THREADS / 64];

    const int bid   = blockIdx.x;
    const int b     = bid >> 5;            // 32 blocks per batch
    const int chunk = bid & 31;
    const int t     = (int)threadIdx.x;

    const float* __restrict__ pos_b = positions + (size_t)b * N_ * 3;
    const float* __restrict__ off_b = offsets   + (size_t)b * PER_BATCH * 3;
    const int*   __restrict__ nb_b  = neighbors + (size_t)b * PER_BATCH;
    const int*   __restrict__ mk_b  = mask      + (size_t)b * PER_BATCH;

    // ---- stage this batch's positions into LDS (SoA) ----
    #pragma unroll
    for (int r = 0; r < N_; r += THREADS) {
        const int row = r + t;
        sx[row] = pos_b[3 * (size_t)row + 0];
        sy[row] = pos_b[3 * (size_t)row + 1];
        sz[row] = pos_b[3 * (size_t)row + 2];
    }
    __syncthreads();

    const float* cb = cell + b * 9;
    const float c00 = cb[0], c01 = cb[1], c02 = cb[2];
    const float c10 = cb[3], c11 = cb[4], c12 = cb[5];
    const float c20 = cb[6], c21 = cb[7], c22 = cb[8];

    const int qbase = chunk * QUADS_PER_BLOCK;
    float acc = 0.0f;

    auto quad = [&](int q) {   // q = quad id within batch
        const i32x4 nb = *(const i32x4*)(nb_b + 4 * (size_t)q);
        const i32x4 mk = *(const i32x4*)(mk_b + 4 * (size_t)q);
        const f32x4 oa = *(const f32x4*)(off_b + 12 * (size_t)q);
        const f32x4 ob = *(const f32x4*)(off_b + 12 * (size_t)q + 4);
        const f32x4 oc = *(const f32x4*)(off_b + 12 * (size_t)q + 8);

        const int n = q / 25;              // 25 quads per row (K=100)
        const float pix = sx[n], piy = sy[n], piz = sz[n];

        auto elem = [&](int m, int j, float o0, float o1, float o2) {
            const float vx = sx[j] + o0 * c00 + o1 * c10 + o2 * c20 - pix;
            const float vy = sy[j] + o0 * c01 + o1 * c11 + o2 * c21 - piy;
            const float vz = sz[j] + o0 * c02 + o1 * c12 + o2 * c22 - piz;
            const float sq = vx * vx + vy * vy + vz * vz;
            const bool keep = (m > 0) & (sq >= RMIN2) & (sq <= RMAX2);
            acc += keep ? (1.0f / sq) : 0.0f;
        };
        elem(mk.x, nb.x, oa.x, oa.y, oa.z);
        elem(mk.y, nb.y, oa.w, ob.x, ob.y);
        elem(mk.z, nb.z, ob.z, ob.w, oc.x);
        elem(mk.w, nb.w, oc.y, oc.z, oc.w);
    };

    #pragma unroll
    for (int k = 0; k < FULL_ITERS; ++k)
        quad(qbase + k * THREADS + t);
    if (t < TAIL)
        quad(qbase + FULL_ITERS * THREADS + t);

    // ---- reduce ----
    #pragma unroll
    for (int off = 32; off > 0; off >>= 1)
        acc += __shfl_down(acc, off, 64);

    const int wave = t >> 6;
    const int lane = t & 63;
    if (lane == 0) wsum[wave] = acc;
    __syncthreads();
    if (t == 0) {
        float s = 0.0f;
        #pragma unroll
        for (int w = 0; w < THREADS / 64; ++w) s += wsum[w];
        atomicAdd(&out[b], 0.5f * s);
    }
}

extern "C" void kernel_launch(void* const* d_in, const int* in_sizes, int n_in,
                              void* d_out, int out_size, void* d_ws, size_t ws_size,
                              hipStream_t stream) {
    const float* positions = (const float*)d_in[0];
    const float* cell      = (const float*)d_in[1];
    const float* offsets   = (const float*)d_in[2];
    const int*   neighbors = (const int*)d_in[3];
    const int*   mask      = (const int*)d_in[4];
    float* out = (float*)d_out;

    (void)hipMemsetAsync(out, 0, out_size * sizeof(float), stream);

    repulsive_prior_kernel<<<GRID, THREADS, 0, stream>>>(
        positions, cell, offsets, neighbors, mask, out);
}